// Round 7
// baseline (331.605 us; speedup 1.0000x reference)
//
#include <hip/hip_runtime.h>

typedef float v2f __attribute__((ext_vector_type(2)));
typedef unsigned long long u64;

#define NPIX 16777216.0

// ---- workspace layout (split path) ----
#define TBITS_OFF 0u
#define EBITS_OFF (2u*1024u*1024u)          // t-bits: 2 MB
#define PART_OFF  (4u*1024u*1024u)          // e-bits: 2 MB
#define NB6       2048                      // loss_stream6 grid
// partials: 5*NB6*4 = 40 KB at PART_OFF

// ---- fallback (fused) geometry ----
#define TW   128
#define TH   32
#define HALO 5
#define TIW  (TW + 2*HALO)
#define TIH  (TH + 2*HALO)
#define TB_P 144
#define VS_P 142
#define NBX  8
#define NBY  32
#define NBZ  16
#define NB   (NBX*NBY*NBZ)

// ============================================================================
// K0: pack target (int32 0/1) into bit plane. 32 px/thread: 8x int4 loads,
// local bit build, one coalesced u32 store. 2048 blocks x 256 threads.
// ============================================================================
__device__ __forceinline__ unsigned nib(int4 r) {
    return (unsigned)((r.x & 1) | ((r.y & 1) << 1) | ((r.z & 1) << 2) | ((r.w & 1) << 3));
}

__global__ __launch_bounds__(256)
void pack_bits32(const int* __restrict__ target, unsigned int* __restrict__ tb32) {
    const int G = blockIdx.x * 256 + threadIdx.x;        // 0..524287
    const int4* p = (const int4*)target + (size_t)G * 8; // 32 consecutive int32
    const int4 r0 = p[0], r1 = p[1], r2 = p[2], r3 = p[3];
    const int4 r4 = p[4], r5 = p[5], r6 = p[6], r7 = p[7];
    unsigned m = nib(r0);
    m |= nib(r1) << 4;
    m |= nib(r2) << 8;
    m |= nib(r3) << 12;
    m |= nib(r4) << 16;
    m |= nib(r5) << 20;
    m |= nib(r6) << 24;
    m |= nib(r7) << 28;
    tb32[G] = m;   // u32 word G covers pixels [32G, 32G+32), little-endian bits
}

// ============================================================================
// K1: edge bits. edge=1 iff 11x11 window (zero-padded) is non-constant,
// i.e. winOR != winAND (== Laplacian != 0 for 0/1 input). Separable:
// vertical OR/AND over 11 rows, then horizontal 11-window via funnel shifts.
// One thread per (batch,row,word): 262144 threads.
// ============================================================================
__device__ __forceinline__ u64 hor11_or(u64 L, u64 M, u64 R) {
    u64 o = M;
    o |= (M >> 1) | (R << 63);
    o |= (M >> 2) | (R << 62);
    o |= (M >> 3) | (R << 61);
    o |= (M >> 4) | (R << 60);
    o |= (M >> 5) | (R << 59);
    o |= (M << 1) | (L >> 63);
    o |= (M << 2) | (L >> 62);
    o |= (M << 3) | (L >> 61);
    o |= (M << 4) | (L >> 60);
    o |= (M << 5) | (L >> 59);
    return o;
}
__device__ __forceinline__ u64 hor11_and(u64 L, u64 M, u64 R) {
    u64 a = M;
    a &= (M >> 1) | (R << 63);
    a &= (M >> 2) | (R << 62);
    a &= (M >> 3) | (R << 61);
    a &= (M >> 4) | (R << 60);
    a &= (M >> 5) | (R << 59);
    a &= (M << 1) | (L >> 63);
    a &= (M << 2) | (L >> 62);
    a &= (M << 3) | (L >> 61);
    a &= (M << 4) | (L >> 60);
    a &= (M << 5) | (L >> 59);
    return a;
}

__global__ __launch_bounds__(256)
void edge_bits(const u64* __restrict__ tbits, u64* __restrict__ ebits) {
    const int idx = blockIdx.x * 256 + threadIdx.x;   // 0..262143
    const int wi  = idx & 15;
    const int row = (idx >> 4) & 1023;
    const int b   = idx >> 14;
    const u64* plane = tbits + (size_t)b * 16384;

    u64 oL = 0, oM = 0, oR = 0;
    u64 aL = ~0ull, aM = ~0ull, aR = ~0ull;
    #pragma unroll
    for (int dr = -5; dr <= 5; ++dr) {
        const int r = row + dr;
        u64 L = 0, M = 0, R = 0;
        if ((unsigned)r < 1024u) {
            const u64* rp = plane + (size_t)r * 16;
            L = (wi > 0)  ? rp[wi - 1] : 0ull;
            M = rp[wi];
            R = (wi < 15) ? rp[wi + 1] : 0ull;
        }
        oL |= L; oM |= M; oR |= R;
        aL &= L; aM &= M; aR &= R;
    }
    const u64 O = hor11_or(oL, oM, oR);
    const u64 A = hor11_and(aL, aM, aR);
    ebits[idx] = O ^ A;
}

// ============================================================================
// K2: streaming loss via global_load_lds DMA staging. 2048 blocks x 256 thr.
// Block owns 8192 px of one batch; 8 tiles x 1024 px; LDS [2][4][1024] f32
// (32 KB double-buffered). Each wave DMAs one plane (4x dwordx4-to-LDS,
// ZERO payload VGPRs) -> in-flight bytes scale with LDS depth, decoupled
// from register budget. Counted vmcnt(4) drain (never 0 mid-loop) + raw
// s_barrier (NOT __syncthreads, which would emit vmcnt(0) and kill the
// prefetch). All mask words preloaded so they don't perturb the count.
// ============================================================================
__device__ __forceinline__ void acc_pair(v2f p0, v2f p1, unsigned t0, unsigned t1,
                                         v2f ef, v2f& s1, v2f& s2) {
    v2f d = p0 - p1;
    v2f sp;
    sp.x = __logf(1.0f + __expf(-fabsf(d.x)));
    sp.y = __logf(1.0f + __expf(-fabsf(d.y)));
    v2f m;
    m.x = fmaxf(p0.x, p1.x);
    m.y = fmaxf(p0.y, p1.y);
    v2f lse = m + sp;
    v2f pt;                          // exact select (no fma reassociation)
    pt.x = t0 ? p1.x : p0.x;
    pt.y = t1 ? p1.y : p0.y;
    v2f lpt = pt - lse;
    v2f slp = (p0 + p1) - 2.0f * lse;
    s1 += lpt;
    s2 += ef * (slp - 1.5f * lpt);
}

__device__ __forceinline__ void proc_group(float4 x0, float4 x1, float4 y0, float4 y1,
                                           unsigned nt, unsigned ne,
                                           v2f& cntv, v2f& a1, v2f& a2, v2f& b1, v2f& b2) {
    #pragma unroll
    for (int h = 0; h < 2; ++h) {
        const unsigned t0 = (nt >> (2 * h)) & 1u;
        const unsigned t1 = (nt >> (2 * h + 1)) & 1u;
        const unsigned e0 = (ne >> (2 * h)) & 1u;
        const unsigned e1 = (ne >> (2 * h + 1)) & 1u;
        v2f ef; ef.x = (float)e0; ef.y = (float)e1;
        cntv += ef;
        v2f p0, p1, q0, q1;
        p0.x = h ? x0.z : x0.x;  p0.y = h ? x0.w : x0.y;
        p1.x = h ? x1.z : x1.x;  p1.y = h ? x1.w : x1.y;
        q0.x = h ? y0.z : y0.x;  q0.y = h ? y0.w : y0.y;
        q1.x = h ? y1.z : y1.x;  q1.y = h ? y1.w : y1.y;
        acc_pair(p0, p1, t0, t1, ef, a1, a2);
        acc_pair(q0, q1, t0, t1, ef, b1, b2);
    }
}

__device__ __forceinline__ void gload16(const float* g, float* l) {
    __builtin_amdgcn_global_load_lds(
        (const __attribute__((address_space(1))) void*)g,
        (__attribute__((address_space(3))) void*)l,
        16, 0, 0);
}

#define WAITV4 asm volatile("s_waitcnt vmcnt(4)" ::: "memory")
#define WAITV0 asm volatile("s_waitcnt vmcnt(0)" ::: "memory")
#define BAR    __builtin_amdgcn_s_barrier()
#define SCHED0 __builtin_amdgcn_sched_barrier(0)

// wave w stages its plane for tile k into lds[b][w][*]; dst is wave-uniform,
// HW writes base + lane*16 (linear), src is per-lane -> layouts match.
#define STAGE6(k, b) \
    gload16(plane + (k) * 1024u +   0u + 4u * lane, &lds[b][w][  0]); \
    gload16(plane + (k) * 1024u + 256u + 4u * lane, &lds[b][w][256]); \
    gload16(plane + (k) * 1024u + 512u + 4u * lane, &lds[b][w][512]); \
    gload16(plane + (k) * 1024u + 768u + 4u * lane, &lds[b][w][768]);

#define MASKL(k) const unsigned tw##k = tb32[gw0 + (k) * 32u], \
                                ew##k = eb32[gw0 + (k) * 32u];

#define COMPT6(k, b) { \
    const float4 X0 = *(const float4*)&lds[b][0][tid4]; \
    const float4 X1 = *(const float4*)&lds[b][1][tid4]; \
    const float4 Y0 = *(const float4*)&lds[b][2][tid4]; \
    const float4 Y1 = *(const float4*)&lds[b][3][tid4]; \
    proc_group(X0, X1, Y0, Y1, (tw##k >> shift) & 15u, (ew##k >> shift) & 15u, \
               cntv, a1, a2, b1, b2); }

__global__ __launch_bounds__(256)
void loss_stream6(const float* __restrict__ score0,
                  const float* __restrict__ score1,
                  const unsigned int* __restrict__ tb32,
                  const unsigned int* __restrict__ eb32,
                  float* __restrict__ partials) {
    __shared__ float lds[2][4][1024];     // 32 KB
    __shared__ float red[4][5];
    const int tid = threadIdx.x;
    const int bid = blockIdx.x;                       // 0..2047
    const int w   = tid >> 6;                         // wave id 0..3 -> plane
    const unsigned lane = (unsigned)(tid & 63);

    const int      bb  = bid >> 7;                    // batch
    const unsigned inb = ((unsigned)bid & 127u) * 8192u;

    // wave's plane: w0=s0c0, w1=s0c1, w2=s1c0, w3=s1c1
    const float* plane = ((w & 2) ? score1 : score0)
                       + (size_t)bb * 2097152u + (unsigned)(w & 1) * 1048576u + inb;

    // mask words for all 8 tiles (preloaded; never perturbs vmcnt count)
    const unsigned gw0   = ((unsigned)bb * 1048576u + inb + 4u * (unsigned)tid) >> 5;
    const unsigned shift = (4u * (unsigned)tid) & 31u;
    MASKL(0) MASKL(1) MASKL(2) MASKL(3) MASKL(4) MASKL(5) MASKL(6) MASKL(7)

    const unsigned tid4 = 4u * (unsigned)tid;

    v2f cntv = {0.f, 0.f}, a1 = {0.f, 0.f}, a2 = {0.f, 0.f};
    v2f b1 = {0.f, 0.f}, b2 = {0.f, 0.f};

    STAGE6(0, 0) STAGE6(1, 1)
    WAITV4; BAR; SCHED0; COMPT6(0, 0); SCHED0; BAR; STAGE6(2, 0)
    WAITV4; BAR; SCHED0; COMPT6(1, 1); SCHED0; BAR; STAGE6(3, 1)
    WAITV4; BAR; SCHED0; COMPT6(2, 0); SCHED0; BAR; STAGE6(4, 0)
    WAITV4; BAR; SCHED0; COMPT6(3, 1); SCHED0; BAR; STAGE6(5, 1)
    WAITV4; BAR; SCHED0; COMPT6(4, 0); SCHED0; BAR; STAGE6(6, 0)
    WAITV4; BAR; SCHED0; COMPT6(5, 1); SCHED0; BAR; STAGE6(7, 1)
    WAITV4; BAR; SCHED0; COMPT6(6, 0); SCHED0;
    WAITV0; BAR; SCHED0; COMPT6(7, 1);

    float vals[5] = {cntv.x + cntv.y, a1.x + a1.y, a2.x + a2.y,
                     b1.x + b1.y, b2.x + b2.y};
    const int lane_ = tid & 63, wv = tid >> 6;
    #pragma unroll
    for (int q = 0; q < 5; ++q) {
        float v = vals[q];
        #pragma unroll
        for (int off = 32; off > 0; off >>= 1) v += __shfl_down(v, off);
        if (lane_ == 0) red[wv][q] = v;
    }
    __syncthreads();
    if (tid == 0) {
        #pragma unroll
        for (int q = 0; q < 5; ++q)
            partials[q * NB6 + bid] = red[0][q] + red[1][q] + red[2][q] + red[3][q];
    }
}

// ---------------- final reduction (n partial sets) ----------------
__global__ __launch_bounds__(1024)
void finalize_loss(const float* __restrict__ ws, float* __restrict__ out, int n) {
    __shared__ double red[16][5];
    const int tid = threadIdx.x;
    double acc[5] = {0, 0, 0, 0, 0};
    for (int i = tid; i < n; i += 1024) {
        #pragma unroll
        for (int q = 0; q < 5; ++q) acc[q] += (double)ws[q * n + i];
    }
    const int lane = tid & 63, wv = tid >> 6;
    #pragma unroll
    for (int q = 0; q < 5; ++q) {
        double v = acc[q];
        #pragma unroll
        for (int off = 32; off > 0; off >>= 1) v += __shfl_down(v, off);
        if (lane == 0) red[wv][q] = v;
    }
    __syncthreads();
    if (tid == 0) {
        double s[5];
        #pragma unroll
        for (int q = 0; q < 5; ++q) {
            double v = 0;
            for (int w = 0; w < 16; ++w) v += red[w][q];
            s[q] = v;
        }
        const double N = NPIX;
        double alpha = s[0] / N;
        if (alpha > 0.2) alpha = 0.2;
        double loss = (s[1] + alpha * s[2]) + 0.5 * (s[3] + alpha * s[4]);
        out[0] = (float)(-loss / N);
    }
}

// ============================================================================
// Fallback: verified fused baseline (workspace too small for bit planes).
// ============================================================================
__global__ __launch_bounds__(256)
void fused_edge_loss(const float* __restrict__ score0,
                     const float* __restrict__ score1,
                     const int*   __restrict__ target,
                     float*       __restrict__ ws) {
    __shared__ unsigned char  tb[TIH][TB_P];
    __shared__ unsigned short vs[TH][VS_P];
    __shared__ float          red[4][5];

    const int tid   = threadIdx.x;
    const int tileX = blockIdx.x * TW;
    const int tileY = blockIdx.y * TH;
    const int b     = blockIdx.z;
    const int bid   = (blockIdx.z * NBY + blockIdx.y) * NBX + blockIdx.x;

    const int* tgt = target + (size_t)b * (1024 * 1024);

    for (int idx = tid; idx < TIH * TIW; idx += 256) {
        int rr = idx / TIW;
        int cc = idx - rr * TIW;
        int gr = tileY + rr - HALO;
        int gc = tileX + cc - HALO;
        unsigned char v = 0;
        if ((unsigned)gr < 1024u && (unsigned)gc < 1024u)
            v = (unsigned char)tgt[gr * 1024 + gc];
        tb[rr][cc] = v;
    }
    __syncthreads();

    if (tid < TIW) {
        int acc = 0;
        #pragma unroll
        for (int rr = 0; rr < 11; ++rr) acc += tb[rr][tid];
        vs[0][tid] = (unsigned short)acc;
        for (int r = 1; r < TH; ++r) {
            acc += (int)tb[r + 10][tid] - (int)tb[r - 1][tid];
            vs[r][tid] = (unsigned short)acc;
        }
    }
    __syncthreads();

    const float* s0b = score0 + (size_t)b * (2 * 1024 * 1024);
    const float* s1b = score1 + (size_t)b * (2 * 1024 * 1024);
    const int tx = tid & 31;
    const int ty = tid >> 5;

    float cnt = 0.f, a1 = 0.f, a2 = 0.f, b1 = 0.f, b2 = 0.f;

    #pragma unroll
    for (int p = 0; p < 4; ++p) {
        const int r  = ty + p * 8;
        const int gr = tileY + r;
        const int c0 = tx * 4;
        const int gc = tileX + c0;

        int S[4];
        int s = 0;
        #pragma unroll
        for (int k = 0; k < 11; ++k) s += vs[r][c0 + k];
        S[0] = s;
        #pragma unroll
        for (int j = 1; j < 4; ++j) {
            s += (int)vs[r][c0 + 10 + j] - (int)vs[r][c0 + j - 1];
            S[j] = s;
        }

        const size_t base = (size_t)gr * 1024 + gc;
        float4 x0 = *(const float4*)(s0b + base);
        float4 x1 = *(const float4*)(s0b + 1048576 + base);
        float4 y0 = *(const float4*)(s1b + base);
        float4 y1 = *(const float4*)(s1b + 1048576 + base);
        float p0a[4] = {x0.x, x0.y, x0.z, x0.w};
        float p1a[4] = {x1.x, x1.y, x1.z, x1.w};
        float q0a[4] = {y0.x, y0.y, y0.z, y0.w};
        float q1a[4] = {y1.x, y1.y, y1.z, y1.w};

        #pragma unroll
        for (int j = 0; j < 4; ++j) {
            const int t = tb[r + 5][c0 + 5 + j];
            const float e = (S[j] != 121 * t) ? 1.0f : 0.0f;
            cnt += e;
            {
                float p0 = p0a[j], p1 = p1a[j];
                float m   = fmaxf(p0, p1);
                float lse = m + __logf(1.0f + __expf(-fabsf(p0 - p1)));
                float lpt = (t ? p1 : p0) - lse;
                float slp = p0 + p1 - 2.0f * lse;
                a1 += lpt;
                a2 += e * (slp - 1.5f * lpt);
            }
            {
                float q0 = q0a[j], q1 = q1a[j];
                float m   = fmaxf(q0, q1);
                float lse = m + __logf(1.0f + __expf(-fabsf(q0 - q1)));
                float lpt = (t ? q1 : q0) - lse;
                float slp = q0 + q1 - 2.0f * lse;
                b1 += lpt;
                b2 += e * (slp - 1.5f * lpt);
            }
        }
    }

    float vals[5] = {cnt, a1, a2, b1, b2};
    const int lane = tid & 63, wv = tid >> 6;
    #pragma unroll
    for (int q = 0; q < 5; ++q) {
        float v = vals[q];
        #pragma unroll
        for (int off = 32; off > 0; off >>= 1) v += __shfl_down(v, off);
        if (lane == 0) red[wv][q] = v;
    }
    __syncthreads();
    if (tid == 0) {
        #pragma unroll
        for (int q = 0; q < 5; ++q) {
            float v = red[0][q] + red[1][q] + red[2][q] + red[3][q];
            ws[q * NB + bid] = v;
        }
    }
}

extern "C" void kernel_launch(void* const* d_in, const int* in_sizes, int n_in,
                              void* d_out, int out_size, void* d_ws, size_t ws_size,
                              hipStream_t stream) {
    const float* score0 = (const float*)d_in[0];
    const float* score1 = (const float*)d_in[1];
    const int*   target = (const int*)d_in[2];
    float* out = (float*)d_out;
    unsigned char* ws = (unsigned char*)d_ws;

    const size_t need = (size_t)PART_OFF + (size_t)5 * NB6 * 4;  // 4 MB + 40 KB
    if (ws_size >= need) {
        unsigned int* tb = (unsigned int*)(ws + TBITS_OFF);
        u64*          eb = (u64*)(ws + EBITS_OFF);
        float*  partials = (float*)(ws + PART_OFF);
        pack_bits32<<<2048, 256, 0, stream>>>(target, tb);
        edge_bits<<<1024, 256, 0, stream>>>((const u64*)tb, eb);
        loss_stream6<<<NB6, 256, 0, stream>>>(score0, score1,
                                              (const unsigned int*)tb,
                                              (const unsigned int*)eb, partials);
        finalize_loss<<<1, 1024, 0, stream>>>(partials, out, NB6);
    } else {
        float* partials = (float*)ws;
        dim3 grid(NBX, NBY, NBZ);
        fused_edge_loss<<<grid, 256, 0, stream>>>(score0, score1, target, partials);
        finalize_loss<<<1, 1024, 0, stream>>>(partials, out, NB);
    }
}